// Round 5
// baseline (7888.685 us; speedup 1.0000x reference)
//
#include <hip/hip_runtime.h>

// PlayerPerformanceGNN: 2-layer GCN (32->16->8) + mean-pool + linear (8->5)
// N=1M, E=16M, G=10k.
// Round 4: value-routing convs. R3 showed the per-edge random 64B gather of
// hs[src] is random-access-throughput-bound (~1.1 TB/s effective, flat vs
// traffic). Replace gather with routing:
//   phase A (k_route): block per SRC bucket -> hs reads are L2-local; bin
//     edges by dst-bucket in LDS, reserve contiguous ranges in a dst-ordered
//     value stream, write val/dIdx as coalesced streaming stores.
//   phase B (k_accum): block per DST bucket -> streaming val/dIdx reads,
//     LDS accumulate, fused norm+bias+ReLU epilogue (+graph-window pool).
// val buffer sized adaptively via K dst-range passes based on ws_size;
// fallback = R3 direct-gather path if workspace too small.

namespace {

constexpr int F_IN = 32, F_H1 = 16, F_H2 = 8, N_CLS = 5;
constexpr int BB = 10, NPB = 1 << BB;
constexpr int MAXB = 1024;
constexpr int CHUNK = 12288;   // binscatter chunk
constexpr int SUBC = 4096;     // route sub-chunk
constexpr int GW = 32;         // pooling graph window

// ---------------- dense matmuls (write hs = dis * (in @ W)) ----------------

__global__ void k_mm1(const float* __restrict__ x, const float* __restrict__ W,
                      const float* __restrict__ dis, float* __restrict__ h, int N) {
  __shared__ float w[F_IN * F_H1];
  for (int k = threadIdx.x; k < F_IN * F_H1; k += blockDim.x) w[k] = W[k];
  __syncthreads();
  int i = blockIdx.x * blockDim.x + threadIdx.x;
  if (i >= N) return;
  const float4* xr = reinterpret_cast<const float4*>(x + (size_t)i * F_IN);
  float acc[F_H1];
#pragma unroll
  for (int f = 0; f < F_H1; ++f) acc[f] = 0.f;
#pragma unroll
  for (int k4 = 0; k4 < F_IN / 4; ++k4) {
    float4 v = xr[k4];
    float vv[4] = {v.x, v.y, v.z, v.w};
#pragma unroll
    for (int j = 0; j < 4; ++j) {
      const float* wr = &w[(k4 * 4 + j) * F_H1];
#pragma unroll
      for (int f = 0; f < F_H1; ++f) acc[f] = fmaf(vv[j], wr[f], acc[f]);
    }
  }
  float s = dis[i];
  float4* hr = reinterpret_cast<float4*>(h + (size_t)i * F_H1);
#pragma unroll
  for (int q = 0; q < F_H1 / 4; ++q)
    hr[q] = make_float4(s * acc[q * 4], s * acc[q * 4 + 1], s * acc[q * 4 + 2],
                        s * acc[q * 4 + 3]);
}

__global__ void k_mm2(const float* __restrict__ in, const float* __restrict__ W,
                      const float* __restrict__ dis, float* __restrict__ h, int N) {
  __shared__ float w[F_H1 * F_H2];
  for (int k = threadIdx.x; k < F_H1 * F_H2; k += blockDim.x) w[k] = W[k];
  __syncthreads();
  int i = blockIdx.x * blockDim.x + threadIdx.x;
  if (i >= N) return;
  const float4* xr = reinterpret_cast<const float4*>(in + (size_t)i * F_H1);
  float acc[F_H2];
#pragma unroll
  for (int f = 0; f < F_H2; ++f) acc[f] = 0.f;
#pragma unroll
  for (int k4 = 0; k4 < F_H1 / 4; ++k4) {
    float4 v = xr[k4];
    float vv[4] = {v.x, v.y, v.z, v.w};
#pragma unroll
    for (int j = 0; j < 4; ++j) {
      const float* wr = &w[(k4 * 4 + j) * F_H2];
#pragma unroll
      for (int f = 0; f < F_H2; ++f) acc[f] = fmaf(vv[j], wr[f], acc[f]);
    }
  }
  float s = dis[i];
  float4* hr = reinterpret_cast<float4*>(h + (size_t)i * F_H2);
#pragma unroll
  for (int q = 0; q < F_H2 / 4; ++q)
    hr[q] = make_float4(s * acc[q * 4], s * acc[q * 4 + 1], s * acc[q * 4 + 2],
                        s * acc[q * 4 + 3]);
}

__global__ void k_final(const float* __restrict__ pooled, const float* __restrict__ cnts,
                        const float* __restrict__ Wl, const float* __restrict__ bl,
                        float* __restrict__ out, int total) {
  int gid = blockIdx.x * blockDim.x + threadIdx.x;
  if (gid >= total) return;
  int g = gid / N_CLS, c = gid % N_CLS;
  float s = 0.f;
#pragma unroll
  for (int f = 0; f < F_H2; ++f) s += pooled[g * F_H2 + f] * Wl[f * N_CLS + c];
  out[gid] = s / fmaxf(cnts[g], 1.f) + bl[c];
}

// ---------------- degrees ----------------

__global__ void k_deg_i(const int* __restrict__ dst, int* __restrict__ deg, int E) {
  int e = blockIdx.x * blockDim.x + threadIdx.x;
  if (e < E) atomicAdd(&deg[dst[e]], 1);
}
__global__ void k_dis_i(const int* __restrict__ deg, float* __restrict__ dis, int N) {
  int i = blockIdx.x * blockDim.x + threadIdx.x;
  if (i < N) dis[i] = rsqrtf((float)deg[i] + 1.0f);
}

// ---------------- bucket build ----------------

__global__ void k_hist(const int* __restrict__ key, int* __restrict__ bcnt,
                       int E, int nbuck) {
  __shared__ int h[MAXB];
  for (int i = threadIdx.x; i < MAXB; i += blockDim.x) h[i] = 0;
  __syncthreads();
  for (int e = blockIdx.x * blockDim.x + threadIdx.x; e < E;
       e += gridDim.x * blockDim.x)
    atomicAdd(&h[key[e] >> BB], 1);
  __syncthreads();
  for (int i = threadIdx.x; i < nbuck; i += blockDim.x)
    if (h[i]) atomicAdd(&bcnt[i], h[i]);
}

__global__ void k_bscan(const int* __restrict__ bcnt, int* __restrict__ bbase,
                        int* __restrict__ bcur, int nbuck, int E) {
  __shared__ int s[MAXB];
  int t = threadIdx.x;
  int v = (t < nbuck) ? bcnt[t] : 0;
  s[t] = v;
  __syncthreads();
  for (int off = 1; off < MAXB; off <<= 1) {
    int x = (t >= off) ? s[t - off] : 0;
    __syncthreads();
    s[t] += x;
    __syncthreads();
  }
  int ex = s[t] - v;
  if (t < nbuck) { bbase[t] = ex; bcur[t] = ex; }
  if (t == 0) bbase[nbuck] = E;
}

// key-bucketed scatter: packed[pos] = (keyLocal<<20)|payload
__global__ __launch_bounds__(256)
void k_binscatter(const int* __restrict__ key, const int* __restrict__ payload,
                  int* __restrict__ bcur, int* __restrict__ packed, int E) {
  __shared__ int hist[MAXB];
  __shared__ int sbase[MAXB];
  __shared__ int lcur[MAXB];
  __shared__ int stg[CHUNK];
  __shared__ int stmp[256];
  int t = threadIdx.x;
  int c0 = blockIdx.x * CHUNK;
  int n = min(CHUNK, E - c0);
  for (int i = t; i < MAXB; i += 256) hist[i] = 0;
  __syncthreads();
  for (int j = t; j < n; j += 256) atomicAdd(&hist[key[c0 + j] >> BB], 1);
  __syncthreads();
  int v[4], sum = 0;
  int b4 = t * 4;
#pragma unroll
  for (int k = 0; k < 4; ++k) { v[k] = hist[b4 + k]; sum += v[k]; }
  stmp[t] = sum;
  __syncthreads();
  for (int off = 1; off < 256; off <<= 1) {
    int x = (t >= off) ? stmp[t - off] : 0;
    __syncthreads();
    stmp[t] += x;
    __syncthreads();
  }
  int run = stmp[t] - sum;
#pragma unroll
  for (int k = 0; k < 4; ++k) { sbase[b4 + k] = run; lcur[b4 + k] = run; run += v[k]; }
  __syncthreads();
  for (int i = t; i < MAXB; i += 256) {
    int c = hist[i];
    if (c) hist[i] = atomicAdd(&bcur[i], c);
  }
  __syncthreads();
  for (int j = t; j < n; j += 256) {
    int kk = key[c0 + j], pl = payload[c0 + j];
    int b = kk >> BB;
    int p = atomicAdd(&lcur[b], 1);
    stg[p] = ((kk & (NPB - 1)) << 20) | pl;
  }
  __syncthreads();
  for (int j = t; j < n; j += 256) {
    int lo = 0, hi = MAXB - 1;
    while (lo < hi) {
      int mid = (lo + hi + 1) >> 1;
      if (sbase[mid] <= j) lo = mid; else hi = mid - 1;
    }
    packed[hist[lo] + (j - sbase[lo])] = stg[j];
  }
}

// ---------------- routed conv: phase A ----------------
// block = one src bucket; packed_s[pos] = (srcLocal<<20)|dst.
// Route edges with dstBucket in [rs,re) into val/dIdx at dst-ordered positions.

__global__ void k_vcur_init(int* __restrict__ vcur, const int* __restrict__ bbase_d,
                            int rs, int re) {
  int i = rs + threadIdx.x;
  if (i < re) vcur[i] = bbase_d[i];
}

template <int F>
__global__ __launch_bounds__(512)
void k_route(const int* __restrict__ bbase_s, const int* __restrict__ packed_s,
             const float* __restrict__ hs, int* __restrict__ vcur,
             const int* __restrict__ bbase_d, float* __restrict__ val,
             int* __restrict__ dIdx, int rs, int re) {
  __shared__ int hist[MAXB];   // counts, then global base per bin
  __shared__ int sbase[MAXB];
  __shared__ int lcur[MAXB];
  __shared__ int stg[SUBC];
  __shared__ int spos[SUBC];
  __shared__ int stmp[512];
  int t = threadIdx.x;
  int sb = blockIdx.x;
  int beg = bbase_s[sb], endAll = bbase_s[sb + 1];
  int srcbase = sb << BB;
  int base0 = bbase_d[rs];
  int W = re - rs;
  const int GPB = 512 / F;
  int f = t % F, g = t / F;

  for (int c0 = beg; c0 < endAll; c0 += SUBC) {
    int n = min(SUBC, endAll - c0);
    int pe[SUBC / 512];
    int nIt = (n + 511) / 512;
#pragma unroll
    for (int it = 0; it < SUBC / 512; ++it) {
      int j = it * 512 + t;
      pe[it] = (it < nIt && j < n) ? packed_s[c0 + j] : 0;
    }
    for (int i = t; i < W; i += 512) hist[i] = 0;
    __syncthreads();
    for (int it = 0; it < nIt; ++it) {
      int j = it * 512 + t;
      if (j < n) {
        int b = (pe[it] & 0xFFFFF) >> BB;
        if (b >= rs && b < re) atomicAdd(&hist[b - rs], 1);
      }
    }
    __syncthreads();
    // exclusive scan over W (<=1024), 2 elems/thread
    int v0 = (2 * t < W) ? hist[2 * t] : 0;
    int v1 = (2 * t + 1 < W) ? hist[2 * t + 1] : 0;
    int sum = v0 + v1;
    stmp[t] = sum;
    __syncthreads();
    for (int off = 1; off < 512; off <<= 1) {
      int x = (t >= off) ? stmp[t - off] : 0;
      __syncthreads();
      stmp[t] += x;
      __syncthreads();
    }
    int run = stmp[t] - sum;
    if (2 * t < W) { sbase[2 * t] = run; lcur[2 * t] = run; }
    if (2 * t + 1 < W) { sbase[2 * t + 1] = run + v0; lcur[2 * t + 1] = run + v0; }
    __syncthreads();
    // reserve contiguous global ranges
    for (int i = t; i < W; i += 512) {
      int c = hist[i];
      if (c) hist[i] = atomicAdd(&vcur[rs + i], c);
    }
    __syncthreads();
    // stage in bin order
    for (int it = 0; it < nIt; ++it) {
      int j = it * 512 + t;
      if (j < n) {
        int p = pe[it];
        int b = (p & 0xFFFFF) >> BB;
        if (b >= rs && b < re) {
          int q = atomicAdd(&lcur[b - rs], 1);
          stg[q] = p;
        }
      }
    }
    __syncthreads();
    int m = stmp[511];  // staged (in-range) count
    // resolve positions
    for (int j = t; j < m; j += 512) {
      int lo = 0, hi = W - 1;
      while (lo < hi) {
        int mid = (lo + hi + 1) >> 1;
        if (sbase[mid] <= j) lo = mid; else hi = mid - 1;
      }
      spos[j] = hist[lo] + (j - sbase[lo]) - base0;
    }
    __syncthreads();
    // value write: F lanes per staged edge; hs reads are bucket-local (L1/L2)
    for (int j = g; j < m; j += GPB) {
      int p = stg[j];
      int sL = p >> 20;
      int dL = p & (NPB - 1);
      int pos = spos[j];
      val[(size_t)pos * F + f] = hs[(size_t)(srcbase + sL) * F + f];
      if (f == 0) dIdx[pos] = dL;
    }
    __syncthreads();
  }
}

// ---------------- routed conv: phase B ----------------

template <int F, bool POOL>
__global__ __launch_bounds__(512)
void k_accum(const int* __restrict__ bbase_d, const int* __restrict__ dIdx,
             const float* __restrict__ val, const float* __restrict__ dis,
             const float* __restrict__ hs, const float* __restrict__ bias,
             const int* __restrict__ batch, float* __restrict__ out,
             float* __restrict__ pooled, float* __restrict__ cnts,
             int rs, int N, int G) {
  __shared__ float acc[NPB * F];
  __shared__ float pacc[GW * F_H2];
  __shared__ float pcnt[GW];
  __shared__ int gmin_s;
  int t = threadIdx.x;
  int b = rs + blockIdx.x;
  int node0 = b << BB;
  for (int i = t; i < NPB * F; i += 512) acc[i] = 0.f;
  if (POOL) {
    for (int i = t; i < GW * F_H2; i += 512) pacc[i] = 0.f;
    if (t < GW) pcnt[t] = 0.f;
    if (t == 0) gmin_s = batch[min(node0, N - 1)];
  }
  __syncthreads();
  int beg = bbase_d[b], end = bbase_d[b + 1], base0 = bbase_d[rs];
  const int GPB = 512 / F;
  int f = t % F, g = t / F;
  int e = beg + g;
  for (; e + 3 * GPB < end; e += 4 * GPB) {
    int p0 = e - base0, p1 = p0 + GPB, p2 = p1 + GPB, p3 = p2 + GPB;
    int d0 = dIdx[p0], d1 = dIdx[p1], d2 = dIdx[p2], d3 = dIdx[p3];
    float v0 = val[(size_t)p0 * F + f];
    float v1 = val[(size_t)p1 * F + f];
    float v2 = val[(size_t)p2 * F + f];
    float v3 = val[(size_t)p3 * F + f];
    atomicAdd(&acc[d0 * F + f], v0);
    atomicAdd(&acc[d1 * F + f], v1);
    atomicAdd(&acc[d2 * F + f], v2);
    atomicAdd(&acc[d3 * F + f], v3);
  }
  for (; e < end; e += GPB) {
    int p = e - base0;
    atomicAdd(&acc[dIdx[p] * F + f], val[(size_t)p * F + f]);
  }
  __syncthreads();
  if (!POOL) {
    for (int i = t; i < NPB * F; i += 512) {
      int node = node0 + i / F;
      if (node >= N) continue;
      int ff = i % F;
      float v = fmaf(dis[node], acc[i] + hs[(size_t)node * F + ff], bias[ff]);
      out[(size_t)node * F + ff] = fmaxf(v, 0.f);
    }
  } else {
    int gmin = gmin_s;
    for (int i = t; i < NPB * F; i += 512) {
      int node = node0 + i / F;
      if (node >= N) continue;
      int ff = i % F;
      float v = fmaf(dis[node], acc[i] + hs[(size_t)node * F + ff], bias[ff]);
      v = fmaxf(v, 0.f);
      int gr = batch[node];
      int idx = gr - gmin;
      if (idx >= 0 && idx < GW) {
        atomicAdd(&pacc[idx * F_H2 + ff], v);
        if (ff == 0) atomicAdd(&pcnt[idx], 1.0f);
      } else {
        atomicAdd(&pooled[gr * F_H2 + ff], v);
        if (ff == 0) atomicAdd(&cnts[gr], 1.0f);
      }
    }
    __syncthreads();
    for (int i = t; i < GW * F_H2; i += 512) {
      int gr = gmin + i / F_H2;
      float v = pacc[i];
      if (gr < G && v != 0.f) atomicAdd(&pooled[gr * F_H2 + i % F_H2], v);
    }
    if (t < GW) {
      int gr = gmin + t;
      float c = pcnt[t];
      if (gr < G && c > 0.f) atomicAdd(&cnts[gr], c);
    }
  }
}

// ---------------- fallback: R3 direct-gather convs ----------------

template <int F>
__global__ __launch_bounds__(512)
void k_conv(const int* __restrict__ bbase, const int* __restrict__ packed,
            const float* __restrict__ dis, const float* __restrict__ hs,
            const float* __restrict__ bias, float* __restrict__ out, int N) {
  __shared__ float acc[NPB * F];
  int t = threadIdx.x;
  for (int i = t; i < NPB * F; i += 512) acc[i] = 0.f;
  __syncthreads();
  int b = blockIdx.x;
  int beg = bbase[b], end = bbase[b + 1];
  const int EPI = 512 / F;
  int f = t % F, eg = t / F;
  constexpr int U = 8;
  int e = beg + eg;
  for (; e + (U - 1) * EPI < end; e += U * EPI) {
    int p[U];
    float m[U];
#pragma unroll
    for (int k = 0; k < U; ++k) p[k] = packed[e + k * EPI];
#pragma unroll
    for (int k = 0; k < U; ++k) m[k] = hs[(size_t)(p[k] & 0xFFFFF) * F + f];
#pragma unroll
    for (int k = 0; k < U; ++k) atomicAdd(&acc[(p[k] >> 20) * F + f], m[k]);
  }
  for (; e < end; e += EPI) {
    int p = packed[e];
    atomicAdd(&acc[(p >> 20) * F + f], hs[(size_t)(p & 0xFFFFF) * F + f]);
  }
  __syncthreads();
  int node0 = b << BB;
  for (int i = t; i < NPB * F; i += 512) {
    int node = node0 + i / F;
    if (node >= N) continue;
    int ff = i % F;
    float v = fmaf(dis[node], acc[i] + hs[(size_t)node * F + ff], bias[ff]);
    out[(size_t)node * F + ff] = fmaxf(v, 0.f);
  }
}

__global__ __launch_bounds__(512)
void k_conv_pool(const int* __restrict__ bbase, const int* __restrict__ packed,
                 const float* __restrict__ dis, const float* __restrict__ hs,
                 const float* __restrict__ bias, const int* __restrict__ batch,
                 float* __restrict__ pooled, float* __restrict__ cnts, int N, int G) {
  constexpr int F = F_H2;
  __shared__ float acc[NPB * F];
  __shared__ float pacc[GW * F];
  __shared__ float pcnt[GW];
  __shared__ int gmin_s;
  int t = threadIdx.x;
  for (int i = t; i < NPB * F; i += 512) acc[i] = 0.f;
  for (int i = t; i < GW * F; i += 512) pacc[i] = 0.f;
  if (t < GW) pcnt[t] = 0.f;
  int b = blockIdx.x;
  int node0 = b << BB;
  if (t == 0) gmin_s = batch[min(node0, N - 1)];
  __syncthreads();
  int beg = bbase[b], end = bbase[b + 1];
  const int EPI = 512 / F;
  int f = t % F, eg = t / F;
  constexpr int U = 8;
  int e = beg + eg;
  for (; e + (U - 1) * EPI < end; e += U * EPI) {
    int p[U];
    float m[U];
#pragma unroll
    for (int k = 0; k < U; ++k) p[k] = packed[e + k * EPI];
#pragma unroll
    for (int k = 0; k < U; ++k) m[k] = hs[(size_t)(p[k] & 0xFFFFF) * F + f];
#pragma unroll
    for (int k = 0; k < U; ++k) atomicAdd(&acc[(p[k] >> 20) * F + f], m[k]);
  }
  for (; e < end; e += EPI) {
    int p = packed[e];
    atomicAdd(&acc[(p >> 20) * F + f], hs[(size_t)(p & 0xFFFFF) * F + f]);
  }
  __syncthreads();
  int gmin = gmin_s;
  for (int i = t; i < NPB * F; i += 512) {
    int node = node0 + i / F;
    if (node >= N) continue;
    int ff = i % F;
    float v = fmaf(dis[node], acc[i] + hs[(size_t)node * F + ff], bias[ff]);
    v = fmaxf(v, 0.f);
    int gr = batch[node];
    int idx = gr - gmin;
    if (idx >= 0 && idx < GW) {
      atomicAdd(&pacc[idx * F + ff], v);
      if (ff == 0) atomicAdd(&pcnt[idx], 1.0f);
    } else {
      atomicAdd(&pooled[gr * F + ff], v);
      if (ff == 0) atomicAdd(&cnts[gr], 1.0f);
    }
  }
  __syncthreads();
  for (int i = t; i < GW * F; i += 512) {
    int gr = gmin + i / F;
    float v = pacc[i];
    if (gr < G && v != 0.f) atomicAdd(&pooled[gr * F + i % F], v);
  }
  if (t < GW) {
    int gr = gmin + t;
    float c = pcnt[t];
    if (gr < G && c > 0.f) atomicAdd(&cnts[gr], c);
  }
}

}  // namespace

extern "C" void kernel_launch(void* const* d_in, const int* in_sizes, int n_in,
                              void* d_out, int out_size, void* d_ws, size_t ws_size,
                              hipStream_t stream) {
  const float* x   = (const float*)d_in[0];
  const int* ei    = (const int*)d_in[1];
  const int* batch = (const int*)d_in[2];
  const float* W1 = (const float*)d_in[4];
  const float* b1 = (const float*)d_in[5];
  const float* W2 = (const float*)d_in[6];
  const float* b2 = (const float*)d_in[7];
  const float* Wl = (const float*)d_in[8];
  const float* bl = (const float*)d_in[9];

  const int N = in_sizes[0] / F_IN;   // 1,000,000
  const int E = in_sizes[1] / 2;      // 16,000,000
  const int G = out_size / N_CLS;     // 10,000
  const int* src  = ei;
  const int* dstp = ei + E;

  const int BLK = 256;
  const int nbuck = (N + NPB - 1) >> BB;

  // common tables + arrays
  size_t fixed = (size_t)(6 * MAXB + 16) * 4      // bcnt/bbase/bcur x2 (d,s)
               + (size_t)N * 4                     // deg
               + (size_t)N * 4                     // dis
               + (size_t)E * 4                     // packed (src- or dst-keyed)
               + (size_t)N * F_H1 * 4              // H
               + (size_t)N * F_H1 * 4              // O
               + (size_t)G * (F_H2 + 1) * 4 + 1024;

  // pick smallest K (dst-range passes) whose val/dIdx chunk fits
  int K = 0;
  size_t cap = 0;
  for (int k = 1; k <= 16; k <<= 1) {
    size_t c = (k == 1) ? (size_t)E : (size_t)E / k + (size_t)E / (k * 4) + 65536;
    size_t need = fixed + c * 4 + c * F_H1 * 4;
    if (need <= ws_size) { K = k; cap = c; break; }
  }

  char* p = (char*)d_ws;
  int*   bcnt_d  = (int*)p;   p += (size_t)MAXB * 4;
  int*   bbase_d = (int*)p;   p += (size_t)(MAXB + 8) * 4;
  int*   bcur_d  = (int*)p;   p += (size_t)MAXB * 4;   // vcur in routed path
  int*   bcnt_s  = (int*)p;   p += (size_t)MAXB * 4;
  int*   bbase_s = (int*)p;   p += (size_t)(MAXB + 8) * 4;
  int*   bcur_s  = (int*)p;   p += (size_t)MAXB * 4;
  int*   deg     = (int*)p;   p += (size_t)N * 4;
  float* dis     = (float*)p; p += (size_t)N * 4;
  int*   packed  = (int*)p;   p += (size_t)E * 4;
  float* H       = (float*)p; p += (size_t)N * F_H1 * 4;
  float* O       = (float*)p; p += (size_t)N * F_H1 * 4;
  float* pooled  = (float*)p; p += (size_t)G * F_H2 * 4;
  float* cnts    = (float*)p; p += (size_t)G * 4;
  int*   dIdx    = (int*)p;   p += cap * 4;
  float* val     = (float*)p;

  hipMemsetAsync(deg, 0, (size_t)N * 4, stream);
  hipMemsetAsync(bcnt_d, 0, (size_t)MAXB * 4, stream);
  hipMemsetAsync(bcnt_s, 0, (size_t)MAXB * 4, stream);
  hipMemsetAsync(pooled, 0, ((size_t)G * F_H2 + G) * 4, stream);

  // degrees -> dis
  k_deg_i<<<(E + BLK - 1) / BLK, BLK, 0, stream>>>(dstp, deg, E);
  k_dis_i<<<(N + BLK - 1) / BLK, BLK, 0, stream>>>(deg, dis, N);
  // dst histogram (segment bounds for accumulate phase)
  k_hist<<<2048, BLK, 0, stream>>>(dstp, bcnt_d, E, nbuck);
  k_bscan<<<1, MAXB, 0, stream>>>(bcnt_d, bbase_d, bcur_d, nbuck, E);

  if (K > 0) {
    // routed path: src-bucketed edges
    k_hist<<<2048, BLK, 0, stream>>>(src, bcnt_s, E, nbuck);
    k_bscan<<<1, MAXB, 0, stream>>>(bcnt_s, bbase_s, bcur_s, nbuck, E);
    k_binscatter<<<(E + CHUNK - 1) / CHUNK, BLK, 0, stream>>>(src, dstp, bcur_s,
                                                              packed, E);
    const int Wk = (nbuck + K - 1) / K;

    k_mm1<<<(N + BLK - 1) / BLK, BLK, 0, stream>>>(x, W1, dis, H, N);
    for (int pp = 0; pp < K; ++pp) {
      int rs = pp * Wk, re = min(rs + Wk, nbuck);
      if (rs >= re) break;
      k_vcur_init<<<1, MAXB, 0, stream>>>(bcur_d, bbase_d, rs, re);
      k_route<F_H1><<<nbuck, 512, 0, stream>>>(bbase_s, packed, H, bcur_d,
                                               bbase_d, val, dIdx, rs, re);
      k_accum<F_H1, false><<<re - rs, 512, 0, stream>>>(
          bbase_d, dIdx, val, dis, H, b1, batch, O, nullptr, nullptr, rs, N, G);
    }
    k_mm2<<<(N + BLK - 1) / BLK, BLK, 0, stream>>>(O, W2, dis, H, N);
    for (int pp = 0; pp < K; ++pp) {
      int rs = pp * Wk, re = min(rs + Wk, nbuck);
      if (rs >= re) break;
      k_vcur_init<<<1, MAXB, 0, stream>>>(bcur_d, bbase_d, rs, re);
      k_route<F_H2><<<nbuck, 512, 0, stream>>>(bbase_s, packed, H, bcur_d,
                                               bbase_d, val, dIdx, rs, re);
      k_accum<F_H2, true><<<re - rs, 512, 0, stream>>>(
          bbase_d, dIdx, val, dis, H, b2, batch, nullptr, pooled, cnts, rs, N, G);
    }
  } else {
    // fallback: R3 direct-gather path (dst-bucketed packed)
    k_binscatter<<<(E + CHUNK - 1) / CHUNK, BLK, 0, stream>>>(dstp, src, bcur_d,
                                                              packed, E);
    k_mm1<<<(N + BLK - 1) / BLK, BLK, 0, stream>>>(x, W1, dis, H, N);
    k_conv<F_H1><<<nbuck, 512, 0, stream>>>(bbase_d, packed, dis, H, b1, O, N);
    k_mm2<<<(N + BLK - 1) / BLK, BLK, 0, stream>>>(O, W2, dis, H, N);
    k_conv_pool<<<nbuck, 512, 0, stream>>>(bbase_d, packed, dis, H, b2, batch,
                                           pooled, cnts, N, G);
  }

  k_final<<<(G * N_CLS + BLK - 1) / BLK, BLK, 0, stream>>>(
      pooled, cnts, Wl, bl, (float*)d_out, G * N_CLS);
}